// Round 17
// baseline (119.209 us; speedup 1.0000x reference)
//
#include <hip/hip_runtime.h>
#include <hip/hip_cooperative_groups.h>
#include <math.h>

namespace cg = cooperative_groups;

#define KMAX   32
#define CIN    64
#define COUT   64
#define NKERN  27
#define GPW    8          // points per wave, gather kernel
#define MMT    2          // 16-row tiles per wave, fused mm kernel
constexpr float BN_EPS = 1e-5f;

typedef _Float16 f16;
typedef _Float16 f16x2 __attribute__((ext_vector_type(2)));
typedef _Float16 f16x8 __attribute__((ext_vector_type(8)));
typedef float    f32x4 __attribute__((ext_vector_type(4)));

union h2i { f16x2 h; int i; };

// ------- kernel A: cvt f32->f16  ||  pack indices (block-split) -------
// packed pk = (idx<<7) | (flt<<25), stored DEINTERLEAVED per point:
//   ints [0..15]  = even neighbors, ints [16..31] = odd neighbors.
// gather byte-off = (pk & 0xFFFFFF) + cpos*4  (f16x2 of channels 2c,2c+1)
// sw(f16) LDS byte-off = (pk>>25)*128 + cpos*4
__global__ __launch_bounds__(256) void k_cvtpack(
    const float* __restrict__ in,          // [N*64] f32
    f16*         __restrict__ out,         // [(N+1)*64] f16
    const float* __restrict__ dw,
    f16*         __restrict__ dwf,
    float*       __restrict__ stats,
    const int*   __restrict__ nn_count,
    const int*   __restrict__ nn_index,
    const int*   __restrict__ filt_index,
    int*         __restrict__ packed,
    float*       __restrict__ invc,
    int total4, int cvtBlocks, int total_q, int zrowIdx)
{
    const int bid = blockIdx.x;
    if (bid == 0) {
        const int t = threadIdx.x;
        if (t < 128) stats[t] = 0.0f;
        if (t < CIN) out[(size_t)zrowIdx * CIN + t] = (f16)0.0f;   // zeros row
        for (int i = t; i < 512; i += 256) {       // dwf B-frag pack
            const int j = i >> 7, s = (i >> 6) & 1, l = i & 63;
            const int col = j * 16 + (l & 15);
            const int k0  = s * 32 + ((l >> 4) * 8);
            #pragma unroll
            for (int e = 0; e < 8; ++e)
                dwf[(size_t)i * 8 + e] = (f16)dw[(k0 + e) * COUT + col];
        }
    }
    if (bid < cvtBlocks) {
        const int stride = cvtBlocks * 256;
        for (int i = bid * 256 + threadIdx.x; i < total4; i += stride) {
            const float4 v = ((const float4*)in)[i];
            f16x2 a = { (f16)v.x, (f16)v.y };
            f16x2 b = { (f16)v.z, (f16)v.w };
            uint2 u;
            u.x = *(const unsigned int*)&a;
            u.y = *(const unsigned int*)&b;
            ((uint2*)out)[i] = u;
        }
    } else {
        const int t = (bid - cvtBlocks) * 256 + threadIdx.x;
        if (t < total_q) {
            const int n = t >> 3, q = t & 7;       // k = 4q .. 4q+3
            const int cnt = nn_count[n];
            const int4 ni = ((const int4*)nn_index)[t];
            const int4 fi = ((const int4*)filt_index)[t];
            const int k0 = q * 4;
            const int px = (((k0 + 0) < cnt ? ni.x : zrowIdx) << 7) | (fi.x << 25);
            const int py = (((k0 + 1) < cnt ? ni.y : zrowIdx) << 7) | (fi.y << 25);
            const int pz = (((k0 + 2) < cnt ? ni.z : zrowIdx) << 7) | (fi.z << 25);
            const int pw = (((k0 + 3) < cnt ? ni.w : zrowIdx) << 7) | (fi.w << 25);
            int* bp = packed + (size_t)n * KMAX;
            int2 ev = { px, pz };
            int2 od = { py, pw };
            *(int2*)(bp + 2 * q)      = ev;
            *(int2*)(bp + 16 + 2 * q) = od;
            if (q == 0) invc[n] = 1.0f / (float)cnt;
        }
    }
}

// ------- kernel G: pair-row gather + spatial filter (R16, 59.8us) -----
__global__ __launch_bounds__(256, 8) void k_gather(
    const f16*   __restrict__ gh,          // f16[(N+1),64], row N = zeros
    const float* __restrict__ sw,          // [27,64] f32
    const int*   __restrict__ packed,      // [N,32] deinterleaved
    const float* __restrict__ invc,        // [N] 1/cnt
    f16*         __restrict__ sp)          // [N,64] out
{
    __shared__ f16 sw_lds[NKERN * CIN];    // 3.4 KB, f16
    const int tid = threadIdx.x;
    for (int i = tid; i < NKERN * CIN; i += 256) sw_lds[i] = (f16)sw[i];
    __syncthreads();

    const int wave = tid >> 6;
    const int lane = tid & 63;
    const int h    = lane >> 5;
    const unsigned cpos4 = (unsigned)(lane & 31) * 4;
    const int base = blockIdx.x * (4 * GPW) + wave * GPW;
    const char* __restrict__ ghb = (const char*)gh;
    const char* __restrict__ swb = (const char*)sw_lds;

    for (int p = 0; p < GPW; ++p) {
        const int n = base + p;
        const int4* __restrict__ pk4 =
            (const int4*)(packed + (size_t)n * KMAX + h * 16);

        int mypk[16];
        #pragma unroll
        for (int q = 0; q < 4; ++q) *(int4*)&mypk[4 * q] = pk4[q];
        const float ic = invc[n];

        f16x2 g2[16];
        #pragma unroll
        for (int i = 0; i < 16; ++i)
            g2[i] = *(const f16x2*)(ghb + (((unsigned)mypk[i] & 0xFFFFFFu) + cpos4));

        f16x2 a0 = {(f16)0.f, (f16)0.f}, a1 = a0, a2 = a0, a3 = a0;
        #pragma unroll
        for (int i = 0; i < 16; ++i) {
            const unsigned swoff = (((unsigned)mypk[i] >> 25) << 7) + cpos4;
            const f16x2 w2 = *(const f16x2*)(swb + swoff);
            f16x2& a = (i & 3) == 0 ? a0 : (i & 3) == 1 ? a1
                     : (i & 3) == 2 ? a2 : a3;
            a = __builtin_elementwise_fma(g2[i], w2, a);   // v_pk_fma_f16
        }
        f16x2 stot = (a0 + a1) + (a2 + a3);

        h2i cv; cv.h = stot;
        h2i ov; ov.i = __shfl_xor(cv.i, 32);
        stot = stot + ov.h;

        if (h == 0) {
            f16x2 res = { (f16)((float)stot.x * ic), (f16)((float)stot.y * ic) };
            *(f16x2*)(sp + (size_t)n * CIN + (cpos4 >> 1)) = res;
        }
    }
}

// ---------------- A-frag loader -----------------------------
// A-frag: lane holds sp[r0 + (l&15)][(l>>4)*8 + e (+32)]  (contiguous f16x8)
// C-frag: row = (l>>4)*4 + r, col = j*16 + (l&15)          (m89-verified)
#define MM_LOAD_AB(r0)                                                        \
    const f16* arow = sp + (size_t)((r0) + (lane & 15)) * CIN + ((lane >> 4) * 8); \
    const f16x8 a0 = *(const f16x8*)(arow);                                   \
    const f16x8 a1 = *(const f16x8*)(arow + 32);

// ------- kernel M: cooperative fused MFMA + relu + BN -----------------
// Phase 1: x = relu(sp @ dw + bias) kept in registers; stats via
// block-reduce + atomics. grid.sync(). Phase 2: per-thread finalize from
// stats, write normalized out. One sp read, one dwf read, zero recompute.
__global__ __launch_bounds__(256, 4) void k_mm_fused(
    const f16*   __restrict__ sp,          // [N,64]
    const f16*   __restrict__ dwf,         // packed B-frags
    const float* __restrict__ bias,        // [1,64]
    const float* __restrict__ gamma,       // [64]
    const float* __restrict__ beta,        // [64]
    float*       __restrict__ stats,       // [128]
    float*       __restrict__ out,         // [N,64]
    float invN)
{
    __shared__ float rsum[4][4][16], rsq[4][4][16];
    const int tid = threadIdx.x;
    const int wave = tid >> 6, lane = tid & 63;

    const f16x8* dwf8 = (const f16x8*)dwf;
    f16x8 b[4][2];
    #pragma unroll
    for (int j = 0; j < 4; ++j) {
        b[j][0] = dwf8[(j * 2 + 0) * 64 + lane];
        b[j][1] = dwf8[(j * 2 + 1) * 64 + lane];
    }
    float bias_c[4];
    #pragma unroll
    for (int j = 0; j < 4; ++j) bias_c[j] = bias[j * 16 + (lane & 15)];

    float xv[MMT][4][4];                   // statically indexed (unrolled)
    float sum[4] = {0, 0, 0, 0}, sq[4] = {0, 0, 0, 0};
    const int rowbase = (blockIdx.x * 4 + wave) * (MMT * 16);

    #pragma unroll
    for (int t = 0; t < MMT; ++t) {
        MM_LOAD_AB(rowbase + t * 16)
        #pragma unroll
        for (int j = 0; j < 4; ++j) {
            f32x4 acc = {0.f, 0.f, 0.f, 0.f};
            acc = __builtin_amdgcn_mfma_f32_16x16x32_f16(a0, b[j][0], acc, 0, 0, 0);
            acc = __builtin_amdgcn_mfma_f32_16x16x32_f16(a1, b[j][1], acc, 0, 0, 0);
            #pragma unroll
            for (int r = 0; r < 4; ++r) {
                const float x = fmaxf(acc[r] + bias_c[j], 0.0f);
                xv[t][j][r] = x;
                sum[j] += x;
                sq[j]  += x * x;
            }
        }
    }

    #pragma unroll
    for (int j = 0; j < 4; ++j) {
        sum[j] += __shfl_xor(sum[j], 16); sum[j] += __shfl_xor(sum[j], 32);
        sq[j]  += __shfl_xor(sq[j], 16);  sq[j]  += __shfl_xor(sq[j], 32);
    }
    if (lane < 16) {
        #pragma unroll
        for (int j = 0; j < 4; ++j) {
            rsum[wave][j][lane] = sum[j];
            rsq[wave][j][lane]  = sq[j];
        }
    }
    __syncthreads();
    if (wave == 0 && lane < 16) {
        #pragma unroll
        for (int j = 0; j < 4; ++j) {
            const float s = rsum[0][j][lane] + rsum[1][j][lane]
                          + rsum[2][j][lane] + rsum[3][j][lane];
            const float q = rsq[0][j][lane] + rsq[1][j][lane]
                          + rsq[2][j][lane] + rsq[3][j][lane];
            atomicAdd(&stats[j * 16 + lane], s);
            atomicAdd(&stats[COUT + j * 16 + lane], q);
        }
    }

    __threadfence();
    cg::this_grid().sync();

    float sc[4], sh[4];
    #pragma unroll
    for (int j = 0; j < 4; ++j) {
        const int c = j * 16 + (lane & 15);
        const float mean = stats[c] * invN;
        const float var  = stats[COUT + c] * invN - mean * mean;
        const float s    = gamma[c] * rsqrtf(var + BN_EPS);
        sc[j] = s;
        sh[j] = beta[c] - mean * s;
    }

    #pragma unroll
    for (int t = 0; t < MMT; ++t) {
        const int r0 = rowbase + t * 16;
        #pragma unroll
        for (int j = 0; j < 4; ++j) {
            #pragma unroll
            for (int r = 0; r < 4; ++r) {
                out[(size_t)(r0 + (lane >> 4) * 4 + r) * COUT + j * 16 + (lane & 15)]
                    = fmaf(xv[t][j][r], sc[j], sh[j]);
            }
        }
    }
}

extern "C" void kernel_launch(void* const* d_in, const int* in_sizes, int n_in,
                              void* d_out, int out_size, void* d_ws, size_t ws_size,
                              hipStream_t stream) {
    const float* inputs     = (const float*)d_in[0];
    const float* sw         = (const float*)d_in[1];
    const float* dw         = (const float*)d_in[2];
    const float* bias       = (const float*)d_in[3];
    const float* gamma      = (const float*)d_in[4];
    const float* beta       = (const float*)d_in[5];
    const int*   nn_count   = (const int*)d_in[6];
    const int*   nn_index   = (const int*)d_in[7];
    const int*   filt_index = (const int*)d_in[8];

    const int N = in_sizes[0] / CIN;           // 65536
    float* out   = (float*)d_out;

    // ws: stats(128f) | pad(128f) | in_h((N+1)*64 f16) | sp(N*64 f16)
    //     | dwf(4096 f16) | packed(N*32 int) | invc(N f32)
    float* stats  = (float*)d_ws;
    f16*   in_h   = (f16*)((float*)d_ws + 256);
    f16*   spb    = in_h + (size_t)(N + 1) * CIN;
    f16*   dwf    = spb + (size_t)N * CIN;
    int*   packed = (int*)(dwf + 4096);
    float* invc   = (float*)(packed + (size_t)N * KMAX);

    const int total4    = N * CIN / 4;         // 1048576 float4 groups
    const int cvtBlocks = 2048;
    const int total_q   = N * (KMAX / 4);      // 524288 int4 groups
    const int packBlocks = (total_q + 255) / 256;

    k_cvtpack<<<cvtBlocks + packBlocks, 256, 0, stream>>>(
        inputs, in_h, dw, dwf, stats,
        nn_count, nn_index, filt_index, packed, invc,
        total4, cvtBlocks, total_q, N);

    k_gather<<<N / (4 * GPW), 256, 0, stream>>>(in_h, sw, packed, invc, spb);

    // fused MFMA + BN (cooperative: grid-wide sync between stats and apply)
    const f16* sp_c    = spb;
    const f16* dwf_c   = dwf;
    float invN = 1.0f / (float)N;
    void* args[] = { (void*)&sp_c, (void*)&dwf_c, (void*)&bias, (void*)&gamma,
                     (void*)&beta, (void*)&stats, (void*)&out, (void*)&invN };
    hipLaunchCooperativeKernel((const void*)k_mm_fused,
                               dim3(N / (4 * MMT * 16)), dim3(256),
                               args, 0, stream);
}

// Round 18
// 58.185 us; speedup vs baseline: 2.0488x; 2.0488x over previous
//
#include <hip/hip_runtime.h>
#include <math.h>

#define KMAX   32
#define CIN    64
#define COUT   64
#define NKERN  27
#define GPW    8          // points per wave, gather kernel
#define MMT    2          // 16-row tiles per wave, matmul kernels
constexpr float BN_EPS = 1e-5f;

typedef _Float16 f16;
typedef _Float16 f16x2 __attribute__((ext_vector_type(2)));
typedef _Float16 f16x8 __attribute__((ext_vector_type(8)));
typedef float    f32x4 __attribute__((ext_vector_type(4)));

union h2i { f16x2 h; int i; };

// ------- kernel A: cvt f32->f16  ||  pack indices (block-split) -------
// packed pk = (idx<<7) | (flt<<25), stored DEINTERLEAVED per point:
//   ints [0..15]  = even neighbors (k = 0,2,...,30)
//   ints [16..31] = odd  neighbors (k = 1,3,...,31)
// gather byte-off = (pk & 0xFFFFFF) + cpos*4  (f16x2 of channels 2c,2c+1)
// sw(f16) LDS byte-off = (pk>>25)*128 + cpos*4
__global__ __launch_bounds__(256) void k_cvtpack(
    const float* __restrict__ in,          // [N*64] f32
    f16*         __restrict__ out,         // [(N+1)*64] f16
    const float* __restrict__ dw,
    f16*         __restrict__ dwf,
    float*       __restrict__ stats,
    const int*   __restrict__ nn_count,
    const int*   __restrict__ nn_index,
    const int*   __restrict__ filt_index,
    int*         __restrict__ packed,
    float*       __restrict__ invc,
    int total4, int cvtBlocks, int total_q, int zrowIdx)
{
    const int bid = blockIdx.x;
    if (bid == 0) {
        const int t = threadIdx.x;
        if (t < 128) stats[t] = 0.0f;
        if (t < CIN) out[(size_t)zrowIdx * CIN + t] = (f16)0.0f;   // zeros row
        for (int i = t; i < 512; i += 256) {       // dwf B-frag pack
            const int j = i >> 7, s = (i >> 6) & 1, l = i & 63;
            const int col = j * 16 + (l & 15);
            const int k0  = s * 32 + ((l >> 4) * 8);
            #pragma unroll
            for (int e = 0; e < 8; ++e)
                dwf[(size_t)i * 8 + e] = (f16)dw[(k0 + e) * COUT + col];
        }
    }
    if (bid < cvtBlocks) {
        const int stride = cvtBlocks * 256;
        for (int i = bid * 256 + threadIdx.x; i < total4; i += stride) {
            const float4 v = ((const float4*)in)[i];
            f16x2 a = { (f16)v.x, (f16)v.y };
            f16x2 b = { (f16)v.z, (f16)v.w };
            uint2 u;
            u.x = *(const unsigned int*)&a;
            u.y = *(const unsigned int*)&b;
            ((uint2*)out)[i] = u;
        }
    } else {
        const int t = (bid - cvtBlocks) * 256 + threadIdx.x;
        if (t < total_q) {
            const int n = t >> 3, q = t & 7;       // k = 4q .. 4q+3
            const int cnt = nn_count[n];
            const int4 ni = ((const int4*)nn_index)[t];
            const int4 fi = ((const int4*)filt_index)[t];
            const int k0 = q * 4;
            const int px = (((k0 + 0) < cnt ? ni.x : zrowIdx) << 7) | (fi.x << 25);
            const int py = (((k0 + 1) < cnt ? ni.y : zrowIdx) << 7) | (fi.y << 25);
            const int pz = (((k0 + 2) < cnt ? ni.z : zrowIdx) << 7) | (fi.z << 25);
            const int pw = (((k0 + 3) < cnt ? ni.w : zrowIdx) << 7) | (fi.w << 25);
            int* bp = packed + (size_t)n * KMAX;
            int2 ev = { px, pz };                  // k even
            int2 od = { py, pw };                  // k odd
            *(int2*)(bp + 2 * q)      = ev;
            *(int2*)(bp + 16 + 2 * q) = od;
            if (q == 0) invc[n] = 1.0f / (float)cnt;
        }
    }
}

// ------- kernel G: pair-row gather + spatial filter (R16, proven) -----
// half h = lane>>5 owns neighbors {2j+h}; deinterleaved pack means each
// lane loads ONLY its 16 indices (4 int4) -- no selects, no pk[32].
// Per point: 4 idx loads + 16 gathers + 16 LDS f16x2 + 16 v_pk_fma_f16.
__global__ __launch_bounds__(256, 8) void k_gather(
    const f16*   __restrict__ gh,          // f16[(N+1),64], row N = zeros
    const float* __restrict__ sw,          // [27,64] f32
    const int*   __restrict__ packed,      // [N,32] deinterleaved
    const float* __restrict__ invc,        // [N] 1/cnt
    f16*         __restrict__ sp)          // [N,64] out
{
    __shared__ f16 sw_lds[NKERN * CIN];    // 3.4 KB, f16
    const int tid = threadIdx.x;
    for (int i = tid; i < NKERN * CIN; i += 256) sw_lds[i] = (f16)sw[i];
    __syncthreads();

    const int wave = tid >> 6;
    const int lane = tid & 63;
    const int h    = lane >> 5;            // which neighbor of each pair
    const unsigned cpos4 = (unsigned)(lane & 31) * 4;  // channel-pair byte off
    const int base = blockIdx.x * (4 * GPW) + wave * GPW;
    const char* __restrict__ ghb = (const char*)gh;
    const char* __restrict__ swb = (const char*)sw_lds;

    for (int p = 0; p < GPW; ++p) {
        const int n = base + p;
        const int4* __restrict__ pk4 =
            (const int4*)(packed + (size_t)n * KMAX + h * 16);

        int mypk[16];
        #pragma unroll
        for (int q = 0; q < 4; ++q) *(int4*)&mypk[4 * q] = pk4[q];
        const float ic = invc[n];

        f16x2 g2[16];
        #pragma unroll
        for (int i = 0; i < 16; ++i)       // 16 independent pair-gathers
            g2[i] = *(const f16x2*)(ghb + (((unsigned)mypk[i] & 0xFFFFFFu) + cpos4));

        f16x2 a0 = {(f16)0.f, (f16)0.f}, a1 = a0, a2 = a0, a3 = a0;
        #pragma unroll
        for (int i = 0; i < 16; ++i) {
            const unsigned swoff = (((unsigned)mypk[i] >> 25) << 7) + cpos4;
            const f16x2 w2 = *(const f16x2*)(swb + swoff);
            f16x2& a = (i & 3) == 0 ? a0 : (i & 3) == 1 ? a1
                     : (i & 3) == 2 ? a2 : a3;
            a = __builtin_elementwise_fma(g2[i], w2, a);   // v_pk_fma_f16
        }
        f16x2 stot = (a0 + a1) + (a2 + a3);

        // cross-half combine: this half's 16 + other half's 16
        h2i cv; cv.h = stot;
        h2i ov; ov.i = __shfl_xor(cv.i, 32);
        stot = stot + ov.h;

        if (h == 0) {
            f16x2 res = { (f16)((float)stot.x * ic), (f16)((float)stot.y * ic) };
            *(f16x2*)(sp + (size_t)n * CIN + (cpos4 >> 1)) = res;
        }
    }
}

// ---------------- MFMA matmul body shared by both passes --------------
// A-frag: lane holds sp[r0 + (l&15)][(l>>4)*8 + e (+32)]  (contiguous f16x8)
// C-frag: row = (l>>4)*4 + r, col = j*16 + (l&15)          (m89-verified)
#define MM_LOAD_AB(r0)                                                        \
    const f16* arow = sp + (size_t)((r0) + (lane & 15)) * CIN + ((lane >> 4) * 8); \
    const f16x8 a0 = *(const f16x8*)(arow);                                   \
    const f16x8 a1 = *(const f16x8*)(arow + 32);

// ---------------- kernel M1: MFMA matmul + relu -> BN stats -----------
__global__ __launch_bounds__(256) void k_mm_stats(
    const f16*   __restrict__ sp,          // [N,64]
    const f16*   __restrict__ dwf,         // packed B-frags
    const float* __restrict__ bias,        // [1,64]
    float*       __restrict__ stats)       // [128]
{
    __shared__ float rsum[4][4][16], rsq[4][4][16];
    const int tid = threadIdx.x;
    const int wave = tid >> 6, lane = tid & 63;

    const f16x8* dwf8 = (const f16x8*)dwf;
    f16x8 b[4][2];
    #pragma unroll
    for (int j = 0; j < 4; ++j) {
        b[j][0] = dwf8[(j * 2 + 0) * 64 + lane];
        b[j][1] = dwf8[(j * 2 + 1) * 64 + lane];
    }
    float bias_c[4];
    #pragma unroll
    for (int j = 0; j < 4; ++j) bias_c[j] = bias[j * 16 + (lane & 15)];

    float sum[4] = {0, 0, 0, 0}, sq[4] = {0, 0, 0, 0};
    const int rowbase = (blockIdx.x * 4 + wave) * (MMT * 16);

    for (int t = 0; t < MMT; ++t) {
        MM_LOAD_AB(rowbase + t * 16)
        #pragma unroll
        for (int j = 0; j < 4; ++j) {
            f32x4 acc = {0.f, 0.f, 0.f, 0.f};
            acc = __builtin_amdgcn_mfma_f32_16x16x32_f16(a0, b[j][0], acc, 0, 0, 0);
            acc = __builtin_amdgcn_mfma_f32_16x16x32_f16(a1, b[j][1], acc, 0, 0, 0);
            #pragma unroll
            for (int r = 0; r < 4; ++r) {
                const float x = fmaxf(acc[r] + bias_c[j], 0.0f);
                sum[j] += x;
                sq[j]  += x * x;
            }
        }
    }

    #pragma unroll
    for (int j = 0; j < 4; ++j) {
        sum[j] += __shfl_xor(sum[j], 16); sum[j] += __shfl_xor(sum[j], 32);
        sq[j]  += __shfl_xor(sq[j], 16);  sq[j]  += __shfl_xor(sq[j], 32);
    }
    if (lane < 16) {
        #pragma unroll
        for (int j = 0; j < 4; ++j) {
            rsum[wave][j][lane] = sum[j];
            rsq[wave][j][lane]  = sq[j];
        }
    }
    __syncthreads();
    if (wave == 0 && lane < 16) {
        #pragma unroll
        for (int j = 0; j < 4; ++j) {
            const float s = rsum[0][j][lane] + rsum[1][j][lane]
                          + rsum[2][j][lane] + rsum[3][j][lane];
            const float q = rsq[0][j][lane] + rsq[1][j][lane]
                          + rsq[2][j][lane] + rsq[3][j][lane];
            atomicAdd(&stats[j * 16 + lane], s);
            atomicAdd(&stats[COUT + j * 16 + lane], q);
        }
    }
}

// ------- kernel M2: MFMA matmul + relu + BN (finalize folded) ---------
// stats[] is complete (k_mm_stats retired); each thread derives its 4
// channels' scale/shift directly -- no separate finalize launch.
__global__ __launch_bounds__(256) void k_mm_out(
    const f16*   __restrict__ sp,          // [N,64]
    const f16*   __restrict__ dwf,         // packed B-frags
    const float* __restrict__ bias,        // [1,64]
    const float* __restrict__ gamma,       // [64]
    const float* __restrict__ beta,        // [64]
    const float* __restrict__ stats,       // [128] raw sums
    float*       __restrict__ out,         // [N,64]
    float invN)
{
    const int tid = threadIdx.x;
    const int wave = tid >> 6, lane = tid & 63;

    const f16x8* dwf8 = (const f16x8*)dwf;
    f16x8 b[4][2];
    #pragma unroll
    for (int j = 0; j < 4; ++j) {
        b[j][0] = dwf8[(j * 2 + 0) * 64 + lane];
        b[j][1] = dwf8[(j * 2 + 1) * 64 + lane];
    }
    float bias_c[4], sc[4], sh[4];
    #pragma unroll
    for (int j = 0; j < 4; ++j) {
        const int c = j * 16 + (lane & 15);
        bias_c[j] = bias[c];
        const float mean = stats[c] * invN;
        const float var  = stats[COUT + c] * invN - mean * mean;
        const float s    = gamma[c] * rsqrtf(var + BN_EPS);
        sc[j] = s;
        sh[j] = beta[c] - mean * s;
    }

    const int rowbase = (blockIdx.x * 4 + wave) * (MMT * 16);
    for (int t = 0; t < MMT; ++t) {
        const int r0 = rowbase + t * 16;
        MM_LOAD_AB(r0)
        #pragma unroll
        for (int j = 0; j < 4; ++j) {
            f32x4 acc = {0.f, 0.f, 0.f, 0.f};
            acc = __builtin_amdgcn_mfma_f32_16x16x32_f16(a0, b[j][0], acc, 0, 0, 0);
            acc = __builtin_amdgcn_mfma_f32_16x16x32_f16(a1, b[j][1], acc, 0, 0, 0);
            #pragma unroll
            for (int r = 0; r < 4; ++r) {
                const float x = fmaxf(acc[r] + bias_c[j], 0.0f);
                out[(size_t)(r0 + (lane >> 4) * 4 + r) * COUT + j * 16 + (lane & 15)]
                    = fmaf(x, sc[j], sh[j]);
            }
        }
    }
}

extern "C" void kernel_launch(void* const* d_in, const int* in_sizes, int n_in,
                              void* d_out, int out_size, void* d_ws, size_t ws_size,
                              hipStream_t stream) {
    const float* inputs     = (const float*)d_in[0];
    const float* sw         = (const float*)d_in[1];
    const float* dw         = (const float*)d_in[2];
    const float* bias       = (const float*)d_in[3];
    const float* gamma      = (const float*)d_in[4];
    const float* beta       = (const float*)d_in[5];
    const int*   nn_count   = (const int*)d_in[6];
    const int*   nn_index   = (const int*)d_in[7];
    const int*   filt_index = (const int*)d_in[8];

    const int N = in_sizes[0] / CIN;           // 65536
    float* out   = (float*)d_out;

    // ws: stats(128f) | pad(128f) | in_h((N+1)*64 f16) | sp(N*64 f16)
    //     | dwf(4096 f16) | packed(N*32 int) | invc(N f32)
    float* stats  = (float*)d_ws;
    f16*   in_h   = (f16*)((float*)d_ws + 256);
    f16*   spb    = in_h + (size_t)(N + 1) * CIN;
    f16*   dwf    = spb + (size_t)N * CIN;
    int*   packed = (int*)(dwf + 4096);
    float* invc   = (float*)(packed + (size_t)N * KMAX);

    const int total4    = N * CIN / 4;         // 1048576 float4 groups
    const int cvtBlocks = 2048;
    const int total_q   = N * (KMAX / 4);      // 524288 int4 groups
    const int packBlocks = (total_q + 255) / 256;

    k_cvtpack<<<cvtBlocks + packBlocks, 256, 0, stream>>>(
        inputs, in_h, dw, dwf, stats,
        nn_count, nn_index, filt_index, packed, invc,
        total4, cvtBlocks, total_q, N);

    k_gather<<<N / (4 * GPW), 256, 0, stream>>>(in_h, sw, packed, invc, spb);

    k_mm_stats<<<N / (4 * MMT * 16), 256, 0, stream>>>(spb, dwf, bias, stats);
    k_mm_out<<<N / (4 * MMT * 16), 256, 0, stream>>>(
        spb, dwf, bias, gamma, beta, stats, out, 1.0f / (float)N);
}